// Round 2
// baseline (909.366 us; speedup 1.0000x reference)
//
#include <hip/hip_runtime.h>
#include <hip/hip_bf16.h>

typedef __attribute__((ext_vector_type(8))) short short8;      // 8 x bf16 (4 VGPR)
typedef __attribute__((ext_vector_type(4))) float f32x4;       // MFMA acc
typedef __attribute__((ext_vector_type(4))) unsigned int u32x4;

static __device__ __forceinline__ unsigned short f2b(float f) {
  unsigned int u = __builtin_bit_cast(unsigned int, f);
  u = (u + 0x7fffu + ((u >> 16) & 1u)) >> 16;   // RNE
  return (unsigned short)u;
}
static __device__ __forceinline__ float b2f(unsigned short h) {
  unsigned int u = ((unsigned int)h) << 16;
  return __builtin_bit_cast(float, u);
}

// ---------------- edge dtype detection ----------------
__global__ void detect_kernel(const int* __restrict__ ew, int* __restrict__ flag) {
  if (threadIdx.x == 0 && blockIdx.x == 0) {
    int z = 0;
#pragma unroll
    for (int i = 1; i < 32; i += 2) z |= ew[i];
    *flag = (z == 0) ? 1 : 0;   // 1 => int64
  }
}

// ---------------- init: deg=1 (self-loop), bucket cursors = 0 ----------------
__global__ __launch_bounds__(256) void init_deg_kernel(int* __restrict__ deg, int n,
                                                       int* __restrict__ bcur) {
  int i = blockIdx.x * 256 + threadIdx.x;
  if (i < n) deg[i] = 1;
  if (blockIdx.x == 0 && threadIdx.x < 8) bcur[threadIdx.x] = 0;
}

// ---------------- fused degree histogram + 8-bucket multisplit staging ----------
// one thread = one edge; wave-ballot compaction -> coalesced staged writes
__global__ __launch_bounds__(256) void degstage_kernel(
    const int* __restrict__ ew, int ne, const int* __restrict__ flag,
    int* __restrict__ deg, unsigned long long* __restrict__ stag,
    int* __restrict__ bcur, int cap, int bshift_div) {
  const int e = blockIdx.x * 256 + threadIdx.x;
  const int lane = threadIdx.x & 63;
  const bool valid = e < ne;
  const int is64 = *flag;
  int s = 0, d = 0, b = 0;
  if (valid) {
    if (is64) {
      s = ew[2 * (size_t)e];
      d = ew[(size_t)2 * ne + 2 * (size_t)e];
    } else {
      s = ew[e];
      d = ew[(size_t)ne + e];
    }
    atomicAdd(&deg[d], 1);
    b = (unsigned)d / (unsigned)bshift_div;   // 0..7
  }
  // per-bucket ballots (all lanes participate)
  unsigned long long m[8];
#pragma unroll
  for (int k = 0; k < 8; ++k) m[k] = __ballot(valid && (b == k));
  int base = 0;
  if (lane < 8) {
    int c = __popcll(m[lane]);
    if (c) base = atomicAdd(&bcur[lane], c);
  }
  int mybase = __shfl(base, b);               // b in [0,8) for valid lanes
  if (valid) {
    unsigned long long lt = (1ull << lane) - 1ull;
    int rank = __popcll(m[b] & lt);
    stag[(size_t)b * cap + mybase + rank] =
        ((unsigned long long)(unsigned)d << 32) | (unsigned)s;
  }
}

// ---------------- parallel scan: block partials ----------------
__global__ __launch_bounds__(256) void partial_kernel(const int* __restrict__ deg,
                                                      int* __restrict__ part, int n) {
  int i = blockIdx.x * 256 + threadIdx.x;
  int v = (i < n) ? deg[i] - 1 : 0;
#pragma unroll
  for (int off = 32; off; off >>= 1) v += __shfl_xor(v, off, 64);
  __shared__ int w[4];
  if ((threadIdx.x & 63) == 0) w[threadIdx.x >> 6] = v;
  __syncthreads();
  if (threadIdx.x == 0) part[blockIdx.x] = w[0] + w[1] + w[2] + w[3];
}

// ---------------- parallel scan: scan the partials (1 block) ----------------
__global__ __launch_bounds__(512) void scanpart_kernel(int* __restrict__ part, int nb) {
  __shared__ int sh[512];
  int t = threadIdx.x;
  int v = (t < nb) ? part[t] : 0;
  sh[t] = v;
  __syncthreads();
  for (int off = 1; off < 512; off <<= 1) {
    int u = (t >= off) ? sh[t - off] : 0;
    __syncthreads();
    sh[t] += u;
    __syncthreads();
  }
  if (t < nb) part[t] = sh[t] - v;   // exclusive
}

// ---------------- parallel scan: fill rowptr/cursor/dinv ----------------
__global__ __launch_bounds__(256) void fill_kernel(const int* __restrict__ deg,
                                                   const int* __restrict__ part,
                                                   int* __restrict__ rowptr,
                                                   int* __restrict__ cursor,
                                                   float* __restrict__ dinv, int n) {
  __shared__ int sh[256];
  int i = blockIdx.x * 256 + threadIdx.x;
  int d = (i < n) ? deg[i] : 1;
  int v = d - 1;
  sh[threadIdx.x] = v;
  __syncthreads();
  for (int off = 1; off < 256; off <<= 1) {
    int t = (threadIdx.x >= off) ? sh[threadIdx.x - off] : 0;
    __syncthreads();
    sh[threadIdx.x] += t;
    __syncthreads();
  }
  int incl = sh[threadIdx.x];
  int excl = incl - v;
  int base = part[blockIdx.x];
  if (i < n) {
    rowptr[i] = base + excl;
    cursor[i] = base + excl;
    dinv[i] = rsqrtf((float)d);
    if (i == n - 1) rowptr[n] = base + incl;
  }
}

// ---------------- phase-2 scatter: bucket -> exact CSR (XCD-local writes) ----
__global__ __launch_bounds__(256) void scatter2_kernel(
    const unsigned long long* __restrict__ stag, const int* __restrict__ bcur,
    int cap, int* __restrict__ cursor, int* __restrict__ csr_src, int blocksPerG) {
  int g = blockIdx.x & 7;                 // bucket == (hoped) XCD via round-robin
  int blkInG = blockIdx.x >> 3;
  int cnt = bcur[g];
  int per = (cnt + blocksPerG - 1) / blocksPerG;
  int lo = blkInG * per;
  int hi = lo + per < cnt ? lo + per : cnt;
  const unsigned long long* sg = stag + (size_t)g * cap;
  for (int i = lo + threadIdx.x; i < hi; i += 256) {
    unsigned long long v = sg[i];
    int s = (int)(v & 0xffffffffu);
    int d = (int)(v >> 32);
    int pos = atomicAdd(&cursor[d], 1);
    csr_src[pos] = s;
  }
}

// ---------------- fallback: simple direct pieces (small ws) ----------------
__global__ __launch_bounds__(256) void deg_kernel(const int* __restrict__ ew, int ne,
                                                  const int* __restrict__ flag,
                                                  int* __restrict__ deg) {
  int e = blockIdx.x * 256 + threadIdx.x;
  if (e >= ne) return;
  const int is64 = *flag;
  int d = is64 ? ew[(size_t)2 * ne + 2 * (size_t)e] : ew[(size_t)ne + e];
  atomicAdd(&deg[d], 1);
}

__global__ __launch_bounds__(256) void scatter_kernel(const int* __restrict__ ew, int ne,
                                                      const int* __restrict__ flag,
                                                      int* __restrict__ cursor,
                                                      int* __restrict__ csr_src) {
  int e = blockIdx.x * 256 + threadIdx.x;
  if (e >= ne) return;
  const int is64 = *flag;
  int s, d;
  if (is64) {
    s = ew[2 * (size_t)e];
    d = ew[(size_t)2 * ne + 2 * (size_t)e];
  } else {
    s = ew[e];
    d = ew[(size_t)ne + e];
  }
  int pos = atomicAdd(&cursor[d], 1);
  csr_src[pos] = s;
}

// ---------------- W_gcn^T cast to bf16: Wt[c][k], c<64, k<512 ----------------
__global__ __launch_bounds__(256) void wt_kernel(const float* __restrict__ Wg,
                                                 unsigned short* __restrict__ Wt) {
  int t = blockIdx.x * 256 + threadIdx.x;   // 32768 total
  int k = t >> 6, c = t & 63;
  Wt[c * 512 + k] = f2b(Wg[t]);             // Wg[k*64 + c]
}

// ---------------- h = bf16(x) @ bf16(W) via MFMA, h stored bf16 ----------------
__global__ __launch_bounds__(256) void gemm_kernel(const float* __restrict__ x,
                                                   const unsigned short* __restrict__ Wt,
                                                   unsigned short* __restrict__ hbf,
                                                   int nnodes) {
  __shared__ unsigned short Bt[64][40];
  const int tid = threadIdx.x;
  const int lane = tid & 63;
  const int wv = tid >> 6;
  const int l15 = lane & 15;
  const int hi = lane >> 4;
  const int rowbase = blockIdx.x * 128 + wv * 32;

  f32x4 acc[2][4] = {};

  for (int kc = 0; kc < 16; ++kc) {
    const int k0 = kc * 32;
    {
      int c = tid >> 2, seg = tid & 3;
      u32x4 v = *reinterpret_cast<const u32x4*>(Wt + c * 512 + k0 + seg * 8);
      *reinterpret_cast<u32x4*>(&Bt[c][seg * 8]) = v;
    }
    __syncthreads();

    short8 afrag[2];
#pragma unroll
    for (int i = 0; i < 2; ++i) {
      int row = rowbase + i * 16 + l15;
      row = row < nnodes ? row : nnodes - 1;
      const float* p = x + (size_t)row * 512 + k0 + hi * 8;
      f32x4 f0 = *reinterpret_cast<const f32x4*>(p);
      f32x4 f1 = *reinterpret_cast<const f32x4*>(p + 4);
      short8 a;
      a[0] = (short)f2b(f0[0]); a[1] = (short)f2b(f0[1]);
      a[2] = (short)f2b(f0[2]); a[3] = (short)f2b(f0[3]);
      a[4] = (short)f2b(f1[0]); a[5] = (short)f2b(f1[1]);
      a[6] = (short)f2b(f1[2]); a[7] = (short)f2b(f1[3]);
      afrag[i] = a;
    }
#pragma unroll
    for (int j = 0; j < 4; ++j) {
      short8 b = *reinterpret_cast<const short8*>(&Bt[j * 16 + l15][hi * 8]);
      acc[0][j] = __builtin_amdgcn_mfma_f32_16x16x32_bf16(afrag[0], b, acc[0][j], 0, 0, 0);
      acc[1][j] = __builtin_amdgcn_mfma_f32_16x16x32_bf16(afrag[1], b, acc[1][j], 0, 0, 0);
    }
    __syncthreads();
  }

#pragma unroll
  for (int i = 0; i < 2; ++i)
#pragma unroll
    for (int j = 0; j < 4; ++j)
#pragma unroll
      for (int r = 0; r < 4; ++r) {
        int row = rowbase + i * 16 + hi * 4 + r;
        if (row < nnodes) hbf[(size_t)row * 64 + j * 16 + l15] = f2b(acc[i][j][r]);
      }
}

// ---------------- aggregate + bias + relu + classifier ----------------
__global__ __launch_bounds__(256) void agg_kernel(const unsigned short* __restrict__ hbf,
                                                  const int* __restrict__ rowptr,
                                                  const int* __restrict__ csr_src,
                                                  const float* __restrict__ dinv,
                                                  const float* __restrict__ b_gcn,
                                                  const float* __restrict__ W_cls,
                                                  const float* __restrict__ b_cls,
                                                  float* __restrict__ out, int n) {
  const int lane = threadIdx.x & 63;
  const int node = blockIdx.x * 4 + (threadIdx.x >> 6);
  if (node >= n) return;

  const float dn = dinv[node];
  float inner = 0.f;
  const int e0 = rowptr[node], e1 = rowptr[node + 1];
  int e = e0;
  for (; e + 4 <= e1; e += 4) {
    int s0 = csr_src[e], s1 = csr_src[e + 1], s2 = csr_src[e + 2], s3 = csr_src[e + 3];
    float w0 = dinv[s0], w1 = dinv[s1], w2 = dinv[s2], w3 = dinv[s3];
    float v0 = b2f(hbf[(size_t)s0 * 64 + lane]);
    float v1 = b2f(hbf[(size_t)s1 * 64 + lane]);
    float v2 = b2f(hbf[(size_t)s2 * 64 + lane]);
    float v3 = b2f(hbf[(size_t)s3 * 64 + lane]);
    inner = fmaf(v0, w0, inner);
    inner = fmaf(v1, w1, inner);
    inner = fmaf(v2, w2, inner);
    inner = fmaf(v3, w3, inner);
  }
  for (; e < e1; ++e) {
    int s = csr_src[e];
    inner = fmaf(b2f(hbf[(size_t)s * 64 + lane]), dinv[s], inner);
  }
  float self = b2f(hbf[(size_t)node * 64 + lane]) * dn;
  float h2 = fmaf(dn, inner + self, b_gcn[lane]);
  h2 = h2 > 0.f ? h2 : 0.f;

  float p[7];
#pragma unroll
  for (int c = 0; c < 7; ++c) p[c] = h2 * W_cls[lane * 7 + c];
#pragma unroll
  for (int off = 32; off; off >>= 1) {
#pragma unroll
    for (int c = 0; c < 7; ++c) p[c] += __shfl_xor(p[c], off, 64);
  }
  if (lane == 0) {
    float* o = out + (size_t)node * 7;
#pragma unroll
    for (int c = 0; c < 7; ++c) o[c] = p[c] + b_cls[c];
  }
}

extern "C" void kernel_launch(void* const* d_in, const int* in_sizes, int n_in,
                              void* d_out, int out_size, void* d_ws, size_t ws_size,
                              hipStream_t stream) {
  const float* x = (const float*)d_in[0];
  const int* ew = (const int*)d_in[1];
  const float* W_gcn = (const float*)d_in[2];
  const float* b_gcn = (const float*)d_in[3];
  const float* W_cls = (const float*)d_in[4];
  const float* b_cls = (const float*)d_in[5];
  float* out = (float*)d_out;

  const int N = in_sizes[0] / 512;              // 100000
  const int NE = in_sizes[1] / 2;               // 3200000

  size_t off = 0;
  auto take = [&](size_t b) { size_t o = off; off += (b + 255) & ~(size_t)255; return o; };
  char* ws = (char*)d_ws;
  int* flag            = (int*)(ws + take(sizeof(int)));
  unsigned short* Wt   = (unsigned short*)(ws + take((size_t)512 * 64 * 2));
  int* cursor          = (int*)(ws + take((size_t)N * 4));
  int* rowptr          = (int*)(ws + take(((size_t)N + 1) * 4));
  float* dinv          = (float*)(ws + take((size_t)N * 4));
  unsigned short* hbf  = (unsigned short*)(ws + take((size_t)N * 64 * 2));
  int* csr_src         = (int*)(ws + take((size_t)NE * 4));
  int* part            = (int*)(ws + take((size_t)512 * 4));
  int* bcur            = (int*)(ws + take((size_t)8 * 4));
  const int cap        = NE / 8 + 32768;        // per-bucket staging capacity
  unsigned long long* stag = (unsigned long long*)(ws + take((size_t)8 * cap * 8));
  const bool big = off <= ws_size;              // staging fits?

  const int nbN = (N + 255) / 256;              // 391
  const int nbE = (NE + 255) / 256;             // 12500
  const int bdiv = (N + 7) / 8;                 // 12500 nodes per bucket

  detect_kernel<<<1, 64, 0, stream>>>(ew, flag);
  init_deg_kernel<<<nbN, 256, 0, stream>>>(cursor, N, bcur);   // cursor holds deg

  if (big) {
    degstage_kernel<<<nbE, 256, 0, stream>>>(ew, NE, flag, cursor, stag, bcur, cap, bdiv);
  } else {
    deg_kernel<<<nbE, 256, 0, stream>>>(ew, NE, flag, cursor);
  }

  // parallel scan: deg(-1) -> rowptr/cursor/dinv
  partial_kernel<<<nbN, 256, 0, stream>>>(cursor, part, N);
  scanpart_kernel<<<1, 512, 0, stream>>>(part, nbN);
  fill_kernel<<<nbN, 256, 0, stream>>>(cursor, part, rowptr, cursor, dinv, N);
  // NOTE: fill reads cursor(=deg) and rewrites cursor in-place; each thread
  // reads its own element before writing it (single pass), so no hazard.

  if (big) {
    const int blocksPerG = 64;
    scatter2_kernel<<<8 * blocksPerG, 256, 0, stream>>>(stag, bcur, cap, cursor, csr_src,
                                                        blocksPerG);
  } else {
    scatter_kernel<<<nbE, 256, 0, stream>>>(ew, NE, flag, cursor, csr_src);
  }

  wt_kernel<<<128, 256, 0, stream>>>(W_gcn, Wt);
  gemm_kernel<<<(N + 127) / 128, 256, 0, stream>>>(x, Wt, hbf, N);
  agg_kernel<<<(N + 3) / 4, 256, 0, stream>>>(hbf, rowptr, csr_src, dinv,
                                              b_gcn, W_cls, b_cls, out, N);
}